// Round 2
// baseline (1104.312 us; speedup 1.0000x reference)
//
#include <hip/hip_runtime.h>
#include <hip/hip_fp16.h>
#include <hip/hip_fp8.h>

#define N_NODES 100000
#define E_EDGES 3200000
#define F_IN 11
#define F_H 64
#define F_E 32

#define BUCKETS ((N_NODES + 255) >> 8)   // 391 coarse buckets (dst>>8)
#define CAP 9216                         // slack bucket capacity (mean ~8184, +11 sigma)
#define CHUNK_A 12288
#define NWG_A ((E_EDGES + CHUNK_A - 1) / CHUNK_A)  // 261
#define EPT 12                           // binA edges per thread (CHUNK_A / 1024)

typedef __attribute__((ext_vector_type(8))) _Float16 f16x8;
typedef __attribute__((ext_vector_type(4))) _Float16 f16x4;
typedef __attribute__((ext_vector_type(4))) float f32x4;
typedef __attribute__((ext_vector_type(2))) float f32x2;

// ---------------- binA: LDS counting-sort -> coalesced global pair writes ----------
// (+ fused x -> fp16 conversion prologue; xh consumed only by the NEXT kernel)
__global__ void binA_kernel(const float* __restrict__ x,
                            const int* __restrict__ src,
                            const int* __restrict__ dst,
                            int* __restrict__ cursor,
                            unsigned int* __restrict__ pairs,
                            _Float16* __restrict__ xh) {
    __shared__ int lh[BUCKETS + 1];
    __shared__ int lstart[BUCKETS + 1];
    __shared__ int lcur[BUCKETS];
    __shared__ int gbase[BUCKETS];
    __shared__ unsigned int stage[CHUNK_A];
    int t = threadIdx.x;

    // fused convert: x [N][11] f32 -> xh [N][12] f16 (zero-padded)
    for (int i = blockIdx.x * 1024 + t; i < N_NODES * 12; i += NWG_A * 1024) {
        int n = i / 12;
        int f = i - n * 12;
        xh[i] = (_Float16)((f < F_IN) ? x[n * F_IN + f] : 0.0f);
    }

    for (int i = t; i <= BUCKETS; i += 1024) lh[i] = 0;
    __syncthreads();

    int e0 = blockIdx.x * CHUNK_A;
    int e1 = min(e0 + CHUNK_A, E_EDGES);

    unsigned int pv[EPT];
    int pb[EPT];
    int cnt = 0;
    for (int i = e0 + t; i < e1; i += 1024) {
        int d = dst[i];
        int b = d >> 8;
        pv[cnt] = (unsigned int)src[i] | (((unsigned int)(d & 255)) << 17);
        pb[cnt] = b;
        ++cnt;
        atomicAdd(&lh[b], 1);
    }
    __syncthreads();

    for (int i = t; i < BUCKETS; i += 1024) lstart[i] = lh[i];
    __syncthreads();
    for (int off = 1; off < 512; off <<= 1) {
        int v = 0;
        if (t < BUCKETS && t >= off) v = lstart[t - off];
        __syncthreads();
        if (t < BUCKETS && t >= off) lstart[t] += v;
        __syncthreads();
    }
    int myIncl = (t < BUCKETS) ? lstart[t] : 0;
    int myCnt  = (t < BUCKETS) ? lh[t] : 0;
    __syncthreads();
    if (t < BUCKETS) {
        int ex = myIncl - myCnt;
        lstart[t] = ex;
        lcur[t] = ex;
        if (myCnt > 0) gbase[t] = t * CAP + atomicAdd(&cursor[t], myCnt);
    }
    if (t == 0) lstart[BUCKETS] = e1 - e0;
    __syncthreads();

    for (int k = 0; k < cnt; ++k) {
        int pos = atomicAdd(&lcur[pb[k]], 1);
        stage[pos] = pv[k];
    }
    __syncthreads();

    int total = e1 - e0;
    for (int i = t; i < total; i += 1024) {
        int lo = 0, hi = BUCKETS;
        while (hi - lo > 1) {
            int mid = (lo + hi) >> 1;
            if (lstart[mid] <= i) lo = mid; else hi = mid;
        }
        pairs[gbase[lo] + (i - lstart[lo])] = stage[i];
    }
}

// ---------------- K2: pair-driven layer-1 mean aggregation via LDS f32 atomics ------
// acc[256][13]: cols 0..11 = feature sums, col 12 = degree count (as float).
// Row stride 13 (coprime with 32) randomizes banks across nodes.
__global__ __launch_bounds__(1024) void agg1_kernel(const unsigned int* __restrict__ pairs,
                                                    const int* __restrict__ cursor,
                                                    const _Float16* __restrict__ xh,
                                                    float* __restrict__ deg_f,
                                                    float* __restrict__ agg1) {
    __shared__ float acc[256][13];
    int b = blockIdx.x;
    int t = threadIdx.x;
    for (int i = t; i < 256 * 13; i += 1024) ((float*)acc)[i] = 0.0f;
    __syncthreads();

    int start = b * CAP;
    int cntAll = cursor[b];
    for (int i = t; i < cntAll; i += 1024) {
        unsigned int p = pairs[start + i];
        int s = p & 0x1FFFF;
        int node = p >> 17;
        const f16x4* r = (const f16x4*)(xh + (size_t)s * 12);
        f16x4 u0 = r[0], u1 = r[1], u2 = r[2];
        float* a = acc[node];
        atomicAdd(&a[12], 1.0f);
        #pragma unroll
        for (int k = 0; k < 4; ++k) {
            atomicAdd(&a[k],     (float)u0[k]);
            atomicAdd(&a[4 + k], (float)u1[k]);
            atomicAdd(&a[8 + k], (float)u2[k]);
        }
    }
    __syncthreads();

    if (t < 256) {
        int node = (b << 8) + t;
        if (node < N_NODES) deg_f[node] = acc[t][12];
    }
    int base = b * 3072;  // 256 * 12
    for (int i = t; i < 3072; i += 1024) {
        int n = i / 12;
        int k = i - n * 12;
        int node = (b << 8) + n;
        if (node < N_NODES) {
            float invd = 1.0f / fmaxf(acc[n][12], 1.0f);
            agg1[base + i] = acc[n][k] * invd;
        }
    }
}

// ---------------- fused layer1 + dual projection via MFMA ----------------
__global__ __launch_bounds__(256) void layer1_proj_kernel(
        const float* __restrict__ x,
        const float* __restrict__ agg1,   // already the MEAN
        const float* __restrict__ W1l,
        const float* __restrict__ W1r,
        const float* __restrict__ b1,
        const float* __restrict__ W2l,
        const float* __restrict__ W2r,
        const float* __restrict__ b2,
        unsigned char* __restrict__ p8,
        float* __restrict__ r2) {
    __shared__ __attribute__((aligned(16))) _Float16 hA1[64][32];
    __shared__ __attribute__((aligned(16))) _Float16 WB1[64][32];
    __shared__ __attribute__((aligned(16))) _Float16 WB2[64][64];
    __shared__ __attribute__((aligned(16))) _Float16 hS[64][64];
    int t = threadIdx.x;
    int n0 = blockIdx.x * 64;

    for (int i = t; i < 64 * 32; i += 256) {
        int n = i >> 5, k = i & 31;
        float v = 0.0f;
        if (k < F_IN) v = W1l[k * F_H + n];
        else if (k < 2 * F_IN) v = W1r[(k - F_IN) * F_H + n];
        WB1[n][k] = (_Float16)v;
    }
    for (int i = t; i < 64 * 64; i += 256) {
        int n = i >> 6, k = i & 63;
        float v = (n < F_E) ? W2l[k * F_E + n] : W2r[k * F_E + (n - F_E)];
        WB2[n][k] = (_Float16)v;
    }
    for (int i = t; i < 64 * 32; i += 256) {
        int nl = i >> 5, k = i & 31;
        int n = n0 + nl;
        if (n >= N_NODES) n = N_NODES - 1;
        float v = 0.0f;
        if (k < F_IN) {
            v = agg1[(size_t)n * 12 + k];
        } else if (k < 2 * F_IN) {
            v = x[n * F_IN + (k - F_IN)];
        }
        hA1[nl][k] = (_Float16)v;
    }
    __syncthreads();

    int lane = t & 63;
    int wave = t >> 6;
    int col = lane & 15;
    int quad = lane >> 4;
    int mbase = wave * 16;

    f16x8 afrag = *(const f16x8*)&hA1[mbase + col][quad * 8];
    #pragma unroll
    for (int nt = 0; nt < 4; ++nt) {
        f16x8 bfrag = *(const f16x8*)&WB1[nt * 16 + col][quad * 8];
        float bias = b1[nt * 16 + col];
        f32x4 acc = {bias, bias, bias, bias};
        acc = __builtin_amdgcn_mfma_f32_16x16x32_f16(afrag, bfrag, acc, 0, 0, 0);
        #pragma unroll
        for (int r = 0; r < 4; ++r)
            hS[mbase + quad * 4 + r][nt * 16 + col] = (_Float16)fmaxf(acc[r], 0.0f);
    }
    __syncthreads();

    f16x8 a0 = *(const f16x8*)&hS[mbase + col][quad * 8];
    f16x8 a1 = *(const f16x8*)&hS[mbase + col][32 + quad * 8];
    #pragma unroll
    for (int nt = 0; nt < 4; ++nt) {
        f16x8 bf0 = *(const f16x8*)&WB2[nt * 16 + col][quad * 8];
        f16x8 bf1 = *(const f16x8*)&WB2[nt * 16 + col][32 + quad * 8];
        f32x4 acc;
        if (nt < 2) {
            acc = (f32x4){0.f, 0.f, 0.f, 0.f};
        } else {
            float bb = b2[(nt - 2) * 16 + col];
            acc = (f32x4){bb, bb, bb, bb};
        }
        acc = __builtin_amdgcn_mfma_f32_16x16x32_f16(a0, bf0, acc, 0, 0, 0);
        acc = __builtin_amdgcn_mfma_f32_16x16x32_f16(a1, bf1, acc, 0, 0, 0);
        #pragma unroll
        for (int r = 0; r < 4; ++r) {
            int node = n0 + mbase + quad * 4 + r;
            if (node < N_NODES) {
                if (nt < 2) {
                    __hip_fp8_e4m3 q((float)acc[r]);
                    p8[(size_t)node * F_E + nt * 16 + col] = (unsigned char)q.__x;
                } else {
                    r2[(size_t)node * F_E + (nt - 2) * 16 + col] = acc[r];
                }
            }
        }
    }
}

// decode 4 packed fp8 e4m3 -> 4 floats (hardware cvt on gfx950)
__device__ inline float4 fp8x4_to_f32(unsigned int w) {
#if defined(__gfx950__) || defined(__gfx942__) || defined(__gfx940__) || defined(__gfx941__)
    f32x2 lo = __builtin_amdgcn_cvt_pk_f32_fp8((int)w, false);
    f32x2 hi = __builtin_amdgcn_cvt_pk_f32_fp8((int)w, true);
    return make_float4(lo[0], lo[1], hi[0], hi[1]);
#else
    __hip_fp8_e4m3 a, b, c, d;
    a.__x = (__hip_fp8_storage_t)(w & 0xFF);
    b.__x = (__hip_fp8_storage_t)((w >> 8) & 0xFF);
    c.__x = (__hip_fp8_storage_t)((w >> 16) & 0xFF);
    d.__x = (__hip_fp8_storage_t)((w >> 24) & 0xFF);
    return make_float4((float)a, (float)b, (float)c, (float)d);
#endif
}

// ---------------- K4: pair-driven layer-2 aggregation via LDS f32 atomics -----------
// acc[256][33]: stride 33 so bank = (node + j) % 32 (stride 32 would put the whole
// wave on one bank per step). Epilogue: mean + residual + relu + emb + logits.
__global__ __launch_bounds__(1024) void layer2_kernel(const unsigned int* __restrict__ pairs,
                                                      const int* __restrict__ cursor,
                                                      const float* __restrict__ deg_f,
                                                      const uint4* __restrict__ p8q,  // [N][2]
                                                      const float* __restrict__ r2,
                                                      const float* __restrict__ Wc,
                                                      const float* __restrict__ bc,
                                                      float* __restrict__ emb,
                                                      float* __restrict__ logits) {
    __shared__ float acc[256][33];
    int b = blockIdx.x;
    int t = threadIdx.x;
    for (int i = t; i < 256 * 33; i += 1024) ((float*)acc)[i] = 0.0f;
    __syncthreads();

    int start = b * CAP;
    int cntAll = cursor[b];
    for (int i = t; i < cntAll; i += 1024) {
        unsigned int p = pairs[start + i];
        int s = p & 0x1FFFF;
        int node = p >> 17;
        uint4 w0 = p8q[(size_t)s * 2];
        uint4 w1 = p8q[(size_t)s * 2 + 1];
        float* a = acc[node];
        float4 v0 = fp8x4_to_f32(w0.x);
        float4 v1 = fp8x4_to_f32(w0.y);
        float4 v2 = fp8x4_to_f32(w0.z);
        float4 v3 = fp8x4_to_f32(w0.w);
        float4 v4 = fp8x4_to_f32(w1.x);
        float4 v5 = fp8x4_to_f32(w1.y);
        float4 v6 = fp8x4_to_f32(w1.z);
        float4 v7 = fp8x4_to_f32(w1.w);
        atomicAdd(&a[0],  v0.x); atomicAdd(&a[1],  v0.y); atomicAdd(&a[2],  v0.z); atomicAdd(&a[3],  v0.w);
        atomicAdd(&a[4],  v1.x); atomicAdd(&a[5],  v1.y); atomicAdd(&a[6],  v1.z); atomicAdd(&a[7],  v1.w);
        atomicAdd(&a[8],  v2.x); atomicAdd(&a[9],  v2.y); atomicAdd(&a[10], v2.z); atomicAdd(&a[11], v2.w);
        atomicAdd(&a[12], v3.x); atomicAdd(&a[13], v3.y); atomicAdd(&a[14], v3.z); atomicAdd(&a[15], v3.w);
        atomicAdd(&a[16], v4.x); atomicAdd(&a[17], v4.y); atomicAdd(&a[18], v4.z); atomicAdd(&a[19], v4.w);
        atomicAdd(&a[20], v5.x); atomicAdd(&a[21], v5.y); atomicAdd(&a[22], v5.z); atomicAdd(&a[23], v5.w);
        atomicAdd(&a[24], v6.x); atomicAdd(&a[25], v6.y); atomicAdd(&a[26], v6.z); atomicAdd(&a[27], v6.w);
        atomicAdd(&a[28], v7.x); atomicAdd(&a[29], v7.y); atomicAdd(&a[30], v7.z); atomicAdd(&a[31], v7.w);
    }
    __syncthreads();

    // epilogue: 4 threads per node, 8 features each
    int n = t >> 2;
    int q = t & 3;
    int node = (b << 8) + n;
    if (node < N_NODES) {
        float invd = 1.0f / fmaxf(deg_f[node], 1.0f);
        const float* rr = r2 + (size_t)node * F_E + 8 * q;
        float e[8];
        #pragma unroll
        for (int j = 0; j < 8; ++j)
            e[j] = fmaxf(acc[n][8 * q + j] * invd + rr[j], 0.0f);
        float4* ep = (float4*)(emb + (size_t)node * F_E + 8 * q);
        ep[0] = make_float4(e[0], e[1], e[2], e[3]);
        ep[1] = make_float4(e[4], e[5], e[6], e[7]);
        float c0 = 0.f, c1 = 0.f, c2 = 0.f;
        #pragma unroll
        for (int j = 0; j < 8; ++j) {
            const float* w = Wc + (8 * q + j) * 3;
            c0 += e[j] * w[0];
            c1 += e[j] * w[1];
            c2 += e[j] * w[2];
        }
        c0 += __shfl_xor(c0, 1); c1 += __shfl_xor(c1, 1); c2 += __shfl_xor(c2, 1);
        c0 += __shfl_xor(c0, 2); c1 += __shfl_xor(c1, 2); c2 += __shfl_xor(c2, 2);
        if (q == 0) {
            logits[(size_t)node * 3 + 0] = c0 + bc[0];
            logits[(size_t)node * 3 + 1] = c1 + bc[1];
            logits[(size_t)node * 3 + 2] = c2 + bc[2];
        }
    }
}

extern "C" void kernel_launch(void* const* d_in, const int* in_sizes, int n_in,
                              void* d_out, int out_size, void* d_ws, size_t ws_size,
                              hipStream_t stream) {
    const float* x   = (const float*)d_in[0];
    const int*   ei  = (const int*)d_in[1];
    const float* W1l = (const float*)d_in[2];
    const float* W1r = (const float*)d_in[3];
    const float* b1  = (const float*)d_in[4];
    const float* W2l = (const float*)d_in[5];
    const float* W2r = (const float*)d_in[6];
    const float* b2  = (const float*)d_in[7];
    const float* Wc  = (const float*)d_in[8];
    const float* bc  = (const float*)d_in[9];

    const int* src = ei;
    const int* dst = ei + E_EDGES;

    float* out    = (float*)d_out;
    float* logits = out;
    float* emb    = out + (size_t)N_NODES * 3;

    // ws layout (4B units):
    //   deg_f (N) | cursor(512) | pairs (BUCKETS*CAP) | r2 (32N) | p8 (8N)
    //   | xh (6N: [N][12] halves) | agg1 (12N)
    int* ws_i     = (int*)d_ws;
    float* deg_f  = (float*)ws_i;
    int* cursor   = ws_i + N_NODES;
    unsigned int* pairs = (unsigned int*)(cursor + 512);
    int* base2    = (int*)(pairs + (size_t)BUCKETS * CAP);
    float* r2     = (float*)base2;                                       // 32N
    unsigned char* p8 = (unsigned char*)(base2 + (size_t)32 * N_NODES);  // 8N units
    _Float16* xh  = (_Float16*)(base2 + (size_t)40 * N_NODES);           // 6N units
    float* agg1   = (float*)(base2 + (size_t)46 * N_NODES);              // 12N

    hipMemsetAsync(cursor, 0, 512 * sizeof(int), stream);

    binA_kernel<<<NWG_A, 1024, 0, stream>>>(x, src, dst, cursor, pairs, xh);
    agg1_kernel<<<BUCKETS, 1024, 0, stream>>>(pairs, cursor, xh, deg_f, agg1);
    layer1_proj_kernel<<<(N_NODES + 63) / 64, 256, 0, stream>>>(
        x, agg1, W1l, W1r, b1, W2l, W2r, b2, p8, r2);
    layer2_kernel<<<BUCKETS, 1024, 0, stream>>>(
        pairs, cursor, deg_f, (const uint4*)p8, r2, Wc, bc, emb, logits);
}

// Round 3
// 220.156 us; speedup vs baseline: 5.0160x; 5.0160x over previous
//
#include <hip/hip_runtime.h>
#include <hip/hip_fp16.h>
#include <hip/hip_fp8.h>

#define N_NODES 100000
#define E_EDGES 3200000
#define F_IN 11
#define F_H 64
#define F_E 32

#define BUCKETS ((N_NODES + 255) >> 8)   // 391 coarse buckets (dst>>8)
#define CAP 9216                         // slack bucket capacity (mean ~8184, +11 sigma)
#define CHUNK_A 12288
#define NWG_A ((E_EDGES + CHUNK_A - 1) / CHUNK_A)  // 261
#define EPT 12                           // binA edges per thread (CHUNK_A / 1024)

// fixed-point scales for integer LDS accumulation
#define SCALE1 32768.0f                  // layer-1 f16 features (rounding ~1.5e-5/add)
#define SCALE2 512.0f                    // layer-2 fp8 values: EXACT (fp8 * 512 is integer)

typedef __attribute__((ext_vector_type(8))) _Float16 f16x8;
typedef __attribute__((ext_vector_type(4))) _Float16 f16x4;
typedef __attribute__((ext_vector_type(4))) float f32x4;
typedef __attribute__((ext_vector_type(2))) float f32x2;

// ---------------- binA: LDS counting-sort -> coalesced global pair writes ----------
// (+ fused x -> fp16 conversion prologue; xh consumed only by the NEXT kernel)
__global__ void binA_kernel(const float* __restrict__ x,
                            const int* __restrict__ src,
                            const int* __restrict__ dst,
                            int* __restrict__ cursor,
                            unsigned int* __restrict__ pairs,
                            _Float16* __restrict__ xh) {
    __shared__ int lh[BUCKETS + 1];
    __shared__ int lstart[BUCKETS + 1];
    __shared__ int lcur[BUCKETS];
    __shared__ int gbase[BUCKETS];
    __shared__ unsigned int stage[CHUNK_A];
    int t = threadIdx.x;

    // fused convert: x [N][11] f32 -> xh [N][12] f16 (zero-padded)
    for (int i = blockIdx.x * 1024 + t; i < N_NODES * 12; i += NWG_A * 1024) {
        int n = i / 12;
        int f = i - n * 12;
        xh[i] = (_Float16)((f < F_IN) ? x[n * F_IN + f] : 0.0f);
    }

    for (int i = t; i <= BUCKETS; i += 1024) lh[i] = 0;
    __syncthreads();

    int e0 = blockIdx.x * CHUNK_A;
    int e1 = min(e0 + CHUNK_A, E_EDGES);

    unsigned int pv[EPT];
    int pb[EPT];
    int cnt = 0;
    for (int i = e0 + t; i < e1; i += 1024) {
        int d = dst[i];
        int b = d >> 8;
        pv[cnt] = (unsigned int)src[i] | (((unsigned int)(d & 255)) << 17);
        pb[cnt] = b;
        ++cnt;
        atomicAdd(&lh[b], 1);
    }
    __syncthreads();

    for (int i = t; i < BUCKETS; i += 1024) lstart[i] = lh[i];
    __syncthreads();
    for (int off = 1; off < 512; off <<= 1) {
        int v = 0;
        if (t < BUCKETS && t >= off) v = lstart[t - off];
        __syncthreads();
        if (t < BUCKETS && t >= off) lstart[t] += v;
        __syncthreads();
    }
    int myIncl = (t < BUCKETS) ? lstart[t] : 0;
    int myCnt  = (t < BUCKETS) ? lh[t] : 0;
    __syncthreads();
    if (t < BUCKETS) {
        int ex = myIncl - myCnt;
        lstart[t] = ex;
        lcur[t] = ex;
        if (myCnt > 0) gbase[t] = t * CAP + atomicAdd(&cursor[t], myCnt);
    }
    if (t == 0) lstart[BUCKETS] = e1 - e0;
    __syncthreads();

    for (int k = 0; k < cnt; ++k) {
        int pos = atomicAdd(&lcur[pb[k]], 1);
        stage[pos] = pv[k];
    }
    __syncthreads();

    int total = e1 - e0;
    for (int i = t; i < total; i += 1024) {
        int lo = 0, hi = BUCKETS;
        while (hi - lo > 1) {
            int mid = (lo + hi) >> 1;
            if (lstart[mid] <= i) lo = mid; else hi = mid;
        }
        pairs[gbase[lo] + (i - lstart[lo])] = stage[i];
    }
}

// ---------------- K2: pair-driven layer-1 mean aggregation, INT LDS atomics ---------
// acc[256][13]: cols 0..11 = fixed-point feature sums (scale 2^15), col 12 = degree.
// Row stride 13 (coprime with 32) spreads banks across nodes.
__global__ __launch_bounds__(1024) void agg1_kernel(const unsigned int* __restrict__ pairs,
                                                    const int* __restrict__ cursor,
                                                    const _Float16* __restrict__ xh,
                                                    float* __restrict__ deg_f,
                                                    float* __restrict__ agg1) {
    __shared__ int acc[256][13];
    int b = blockIdx.x;
    int t = threadIdx.x;
    for (int i = t; i < 256 * 13; i += 1024) ((int*)acc)[i] = 0;
    __syncthreads();

    int start = b * CAP;
    int cntAll = cursor[b];
    for (int i = t; i < cntAll; i += 1024) {
        unsigned int p = pairs[start + i];
        int s = p & 0x1FFFF;
        int node = p >> 17;
        const f16x4* r = (const f16x4*)(xh + (size_t)s * 12);
        f16x4 u0 = r[0], u1 = r[1], u2 = r[2];
        atomicAdd(&acc[node][12], 1);
        #pragma unroll
        for (int k = 0; k < 4; ++k) {
            atomicAdd(&acc[node][k],     __float2int_rn((float)u0[k] * SCALE1));
            atomicAdd(&acc[node][4 + k], __float2int_rn((float)u1[k] * SCALE1));
            atomicAdd(&acc[node][8 + k], __float2int_rn((float)u2[k] * SCALE1));
        }
    }
    __syncthreads();

    if (t < 256) {
        int node = (b << 8) + t;
        if (node < N_NODES) deg_f[node] = (float)acc[t][12];
    }
    int base = b * 3072;  // 256 * 12
    for (int i = t; i < 3072; i += 1024) {
        int n = i / 12;
        int k = i - n * 12;
        int node = (b << 8) + n;
        if (node < N_NODES) {
            float invd = 1.0f / fmaxf((float)acc[n][12], 1.0f);
            agg1[base + i] = (float)acc[n][k] * (invd * (1.0f / SCALE1));
        }
    }
}

// ---------------- fused layer1 + dual projection via MFMA ----------------
__global__ __launch_bounds__(256) void layer1_proj_kernel(
        const float* __restrict__ x,
        const float* __restrict__ agg1,   // already the MEAN
        const float* __restrict__ W1l,
        const float* __restrict__ W1r,
        const float* __restrict__ b1,
        const float* __restrict__ W2l,
        const float* __restrict__ W2r,
        const float* __restrict__ b2,
        unsigned char* __restrict__ p8,
        float* __restrict__ r2) {
    __shared__ __attribute__((aligned(16))) _Float16 hA1[64][32];
    __shared__ __attribute__((aligned(16))) _Float16 WB1[64][32];
    __shared__ __attribute__((aligned(16))) _Float16 WB2[64][64];
    __shared__ __attribute__((aligned(16))) _Float16 hS[64][64];
    int t = threadIdx.x;
    int n0 = blockIdx.x * 64;

    for (int i = t; i < 64 * 32; i += 256) {
        int n = i >> 5, k = i & 31;
        float v = 0.0f;
        if (k < F_IN) v = W1l[k * F_H + n];
        else if (k < 2 * F_IN) v = W1r[(k - F_IN) * F_H + n];
        WB1[n][k] = (_Float16)v;
    }
    for (int i = t; i < 64 * 64; i += 256) {
        int n = i >> 6, k = i & 63;
        float v = (n < F_E) ? W2l[k * F_E + n] : W2r[k * F_E + (n - F_E)];
        WB2[n][k] = (_Float16)v;
    }
    for (int i = t; i < 64 * 32; i += 256) {
        int nl = i >> 5, k = i & 31;
        int n = n0 + nl;
        if (n >= N_NODES) n = N_NODES - 1;
        float v = 0.0f;
        if (k < F_IN) {
            v = agg1[(size_t)n * 12 + k];
        } else if (k < 2 * F_IN) {
            v = x[n * F_IN + (k - F_IN)];
        }
        hA1[nl][k] = (_Float16)v;
    }
    __syncthreads();

    int lane = t & 63;
    int wave = t >> 6;
    int col = lane & 15;
    int quad = lane >> 4;
    int mbase = wave * 16;

    f16x8 afrag = *(const f16x8*)&hA1[mbase + col][quad * 8];
    #pragma unroll
    for (int nt = 0; nt < 4; ++nt) {
        f16x8 bfrag = *(const f16x8*)&WB1[nt * 16 + col][quad * 8];
        float bias = b1[nt * 16 + col];
        f32x4 acc = {bias, bias, bias, bias};
        acc = __builtin_amdgcn_mfma_f32_16x16x32_f16(afrag, bfrag, acc, 0, 0, 0);
        #pragma unroll
        for (int r = 0; r < 4; ++r)
            hS[mbase + quad * 4 + r][nt * 16 + col] = (_Float16)fmaxf(acc[r], 0.0f);
    }
    __syncthreads();

    f16x8 a0 = *(const f16x8*)&hS[mbase + col][quad * 8];
    f16x8 a1 = *(const f16x8*)&hS[mbase + col][32 + quad * 8];
    #pragma unroll
    for (int nt = 0; nt < 4; ++nt) {
        f16x8 bf0 = *(const f16x8*)&WB2[nt * 16 + col][quad * 8];
        f16x8 bf1 = *(const f16x8*)&WB2[nt * 16 + col][32 + quad * 8];
        f32x4 acc;
        if (nt < 2) {
            acc = (f32x4){0.f, 0.f, 0.f, 0.f};
        } else {
            float bb = b2[(nt - 2) * 16 + col];
            acc = (f32x4){bb, bb, bb, bb};
        }
        acc = __builtin_amdgcn_mfma_f32_16x16x32_f16(a0, bf0, acc, 0, 0, 0);
        acc = __builtin_amdgcn_mfma_f32_16x16x32_f16(a1, bf1, acc, 0, 0, 0);
        #pragma unroll
        for (int r = 0; r < 4; ++r) {
            int node = n0 + mbase + quad * 4 + r;
            if (node < N_NODES) {
                if (nt < 2) {
                    __hip_fp8_e4m3 q((float)acc[r]);
                    p8[(size_t)node * F_E + nt * 16 + col] = (unsigned char)q.__x;
                } else {
                    r2[(size_t)node * F_E + (nt - 2) * 16 + col] = acc[r];
                }
            }
        }
    }
}

// decode 4 packed fp8 e4m3 -> 4 floats (hardware cvt on gfx950)
__device__ inline float4 fp8x4_to_f32(unsigned int w) {
#if defined(__gfx950__) || defined(__gfx942__) || defined(__gfx940__) || defined(__gfx941__)
    f32x2 lo = __builtin_amdgcn_cvt_pk_f32_fp8((int)w, false);
    f32x2 hi = __builtin_amdgcn_cvt_pk_f32_fp8((int)w, true);
    return make_float4(lo[0], lo[1], hi[0], hi[1]);
#else
    __hip_fp8_e4m3 a, b, c, d;
    a.__x = (__hip_fp8_storage_t)(w & 0xFF);
    b.__x = (__hip_fp8_storage_t)((w >> 8) & 0xFF);
    c.__x = (__hip_fp8_storage_t)((w >> 16) & 0xFF);
    d.__x = (__hip_fp8_storage_t)((w >> 24) & 0xFF);
    return make_float4((float)a, (float)b, (float)c, (float)d);
#endif
}

// ---------------- K4: pair-driven layer-2 aggregation, INT LDS atomics --------------
// acc[256][33]: stride 33 so bank = (node + j) % 32. fp8 * 512 is an exact integer,
// so the int sum is EXACT. Epilogue: mean + residual + relu + emb + logits.
__global__ __launch_bounds__(1024) void layer2_kernel(const unsigned int* __restrict__ pairs,
                                                      const int* __restrict__ cursor,
                                                      const float* __restrict__ deg_f,
                                                      const uint4* __restrict__ p8q,  // [N][2]
                                                      const float* __restrict__ r2,
                                                      const float* __restrict__ Wc,
                                                      const float* __restrict__ bc,
                                                      float* __restrict__ emb,
                                                      float* __restrict__ logits) {
    __shared__ int acc[256][33];
    int b = blockIdx.x;
    int t = threadIdx.x;
    for (int i = t; i < 256 * 33; i += 1024) ((int*)acc)[i] = 0;
    __syncthreads();

    int start = b * CAP;
    int cntAll = cursor[b];
    for (int i = t; i < cntAll; i += 1024) {
        unsigned int p = pairs[start + i];
        int s = p & 0x1FFFF;
        int node = p >> 17;
        uint4 w0 = p8q[(size_t)s * 2];
        uint4 w1 = p8q[(size_t)s * 2 + 1];
#define ACC4(word, base_) { float4 v = fp8x4_to_f32(word); \
        atomicAdd(&acc[node][(base_) + 0], (int)(v.x * SCALE2)); \
        atomicAdd(&acc[node][(base_) + 1], (int)(v.y * SCALE2)); \
        atomicAdd(&acc[node][(base_) + 2], (int)(v.z * SCALE2)); \
        atomicAdd(&acc[node][(base_) + 3], (int)(v.w * SCALE2)); }
        ACC4(w0.x, 0)  ACC4(w0.y, 4)  ACC4(w0.z, 8)  ACC4(w0.w, 12)
        ACC4(w1.x, 16) ACC4(w1.y, 20) ACC4(w1.z, 24) ACC4(w1.w, 28)
#undef ACC4
    }
    __syncthreads();

    // epilogue: 4 threads per node, 8 features each
    int n = t >> 2;
    int q = t & 3;
    int node = (b << 8) + n;
    if (node < N_NODES) {
        float sc = (1.0f / SCALE2) / fmaxf(deg_f[node], 1.0f);
        const float* rr = r2 + (size_t)node * F_E + 8 * q;
        float e[8];
        #pragma unroll
        for (int j = 0; j < 8; ++j)
            e[j] = fmaxf((float)acc[n][8 * q + j] * sc + rr[j], 0.0f);
        float4* ep = (float4*)(emb + (size_t)node * F_E + 8 * q);
        ep[0] = make_float4(e[0], e[1], e[2], e[3]);
        ep[1] = make_float4(e[4], e[5], e[6], e[7]);
        float c0 = 0.f, c1 = 0.f, c2 = 0.f;
        #pragma unroll
        for (int j = 0; j < 8; ++j) {
            const float* w = Wc + (8 * q + j) * 3;
            c0 += e[j] * w[0];
            c1 += e[j] * w[1];
            c2 += e[j] * w[2];
        }
        c0 += __shfl_xor(c0, 1); c1 += __shfl_xor(c1, 1); c2 += __shfl_xor(c2, 1);
        c0 += __shfl_xor(c0, 2); c1 += __shfl_xor(c1, 2); c2 += __shfl_xor(c2, 2);
        if (q == 0) {
            logits[(size_t)node * 3 + 0] = c0 + bc[0];
            logits[(size_t)node * 3 + 1] = c1 + bc[1];
            logits[(size_t)node * 3 + 2] = c2 + bc[2];
        }
    }
}

extern "C" void kernel_launch(void* const* d_in, const int* in_sizes, int n_in,
                              void* d_out, int out_size, void* d_ws, size_t ws_size,
                              hipStream_t stream) {
    const float* x   = (const float*)d_in[0];
    const int*   ei  = (const int*)d_in[1];
    const float* W1l = (const float*)d_in[2];
    const float* W1r = (const float*)d_in[3];
    const float* b1  = (const float*)d_in[4];
    const float* W2l = (const float*)d_in[5];
    const float* W2r = (const float*)d_in[6];
    const float* b2  = (const float*)d_in[7];
    const float* Wc  = (const float*)d_in[8];
    const float* bc  = (const float*)d_in[9];

    const int* src = ei;
    const int* dst = ei + E_EDGES;

    float* out    = (float*)d_out;
    float* logits = out;
    float* emb    = out + (size_t)N_NODES * 3;

    // ws layout (4B units):
    //   deg_f (N) | cursor(512) | pairs (BUCKETS*CAP) | r2 (32N) | p8 (8N)
    //   | xh (6N: [N][12] halves) | agg1 (12N)
    int* ws_i     = (int*)d_ws;
    float* deg_f  = (float*)ws_i;
    int* cursor   = ws_i + N_NODES;
    unsigned int* pairs = (unsigned int*)(cursor + 512);
    int* base2    = (int*)(pairs + (size_t)BUCKETS * CAP);
    float* r2     = (float*)base2;                                       // 32N
    unsigned char* p8 = (unsigned char*)(base2 + (size_t)32 * N_NODES);  // 8N units
    _Float16* xh  = (_Float16*)(base2 + (size_t)40 * N_NODES);           // 6N units
    float* agg1   = (float*)(base2 + (size_t)46 * N_NODES);              // 12N

    hipMemsetAsync(cursor, 0, 512 * sizeof(int), stream);

    binA_kernel<<<NWG_A, 1024, 0, stream>>>(x, src, dst, cursor, pairs, xh);
    agg1_kernel<<<BUCKETS, 1024, 0, stream>>>(pairs, cursor, xh, deg_f, agg1);
    layer1_proj_kernel<<<(N_NODES + 63) / 64, 256, 0, stream>>>(
        x, agg1, W1l, W1r, b1, W2l, W2r, b2, p8, r2);
    layer2_kernel<<<BUCKETS, 1024, 0, stream>>>(
        pairs, cursor, deg_f, (const uint4*)p8, r2, Wc, bc, emb, logits);
}

// Round 4
// 217.922 us; speedup vs baseline: 5.0675x; 1.0103x over previous
//
#include <hip/hip_runtime.h>
#include <hip/hip_fp16.h>
#include <hip/hip_fp8.h>

#define N_NODES 100000
#define E_EDGES 3200000
#define F_IN 11
#define F_H 64
#define F_E 32

#define BUCKETS ((N_NODES + 255) >> 8)   // 391 coarse buckets (dst>>8)
#define CAP 9216                         // slack bucket capacity (mean ~8184, +11 sigma)
#define CHUNK_A 12288
#define NWG_A ((E_EDGES + CHUNK_A - 1) / CHUNK_A)  // 261
#define EPT 12                           // binA edges per thread (CHUNK_A / 1024)

// fixed-point scales for integer LDS accumulation
#define SCALE1 32768.0f                  // layer-1 f16 features (rounding ~1.5e-5/add)
#define SCALE2 512.0f                    // layer-2 fp8 values: EXACT (fp8 * 512 is integer)

typedef __attribute__((ext_vector_type(8))) _Float16 f16x8;
typedef __attribute__((ext_vector_type(4))) _Float16 f16x4;
typedef __attribute__((ext_vector_type(4))) float f32x4;
typedef __attribute__((ext_vector_type(2))) float f32x2;

// ---------------- binA: LDS histogram -> per-bucket global reservation -> direct
// scattered pair writes. (No stage, no prefix scan, no binary search.)
// (+ fused x -> fp16 conversion prologue; xh consumed only by the NEXT kernel)
__global__ __launch_bounds__(1024) void binA_kernel(const float* __restrict__ x,
                                                    const int* __restrict__ src,
                                                    const int* __restrict__ dst,
                                                    int* __restrict__ cursor,
                                                    unsigned int* __restrict__ pairs,
                                                    _Float16* __restrict__ xh) {
    __shared__ int lh[BUCKETS];     // phase 1: histogram; phase 2: local claim counter
    __shared__ int lbase[BUCKETS];  // reserved global base for this block
    int t = threadIdx.x;

    // fused convert: x [N][11] f32 -> xh [N][12] f16 (zero-padded)
    for (int i = blockIdx.x * 1024 + t; i < N_NODES * 12; i += NWG_A * 1024) {
        int n = i / 12;
        int f = i - n * 12;
        xh[i] = (_Float16)((f < F_IN) ? x[n * F_IN + f] : 0.0f);
    }

    for (int i = t; i < BUCKETS; i += 1024) lh[i] = 0;
    __syncthreads();

    int e0 = blockIdx.x * CHUNK_A;
    int e1 = min(e0 + CHUNK_A, E_EDGES);

    unsigned int pv[EPT];
    int pb[EPT];
    int cnt = 0;
    for (int i = e0 + t; i < e1; i += 1024) {
        int d = dst[i];
        int b = d >> 8;
        pv[cnt] = (unsigned int)src[i] | (((unsigned int)(d & 255)) << 17);
        pb[cnt] = b;
        ++cnt;
        atomicAdd(&lh[b], 1);
    }
    __syncthreads();

    // reserve a contiguous window per touched bucket; reset lh for phase 2.
    // each bucket index is visited by exactly one thread here.
    for (int i = t; i < BUCKETS; i += 1024) {
        int c = lh[i];
        if (c > 0) lbase[i] = i * CAP + atomicAdd(&cursor[i], c);
        lh[i] = 0;
    }
    __syncthreads();

    for (int k = 0; k < cnt; ++k) {
        int b = pb[k];
        int pos = atomicAdd(&lh[b], 1);
        pairs[lbase[b] + pos] = pv[k];
    }
}

// ---------------- K2: pair-driven layer-1 mean aggregation, INT LDS atomics ---------
// 4 lanes per edge: q=0..2 each add 4 features (cols 4q..4q+3), q=3 adds the degree.
// acc[256][13]; stride 13 (coprime 32) spreads banks across nodes; the 4q offset
// spreads intra-edge lanes across banks.
__global__ __launch_bounds__(1024) void agg1_kernel(const unsigned int* __restrict__ pairs,
                                                    const int* __restrict__ cursor,
                                                    const _Float16* __restrict__ xh,
                                                    float* __restrict__ deg_f,
                                                    float* __restrict__ agg1) {
    __shared__ int acc[256][13];
    int b = blockIdx.x;
    int t = threadIdx.x;
    for (int i = t; i < 256 * 13; i += 1024) ((int*)acc)[i] = 0;
    __syncthreads();

    int start = b * CAP;
    int cntAll = cursor[b];
    int q = t & 3;
    for (int i = (t >> 2); i < cntAll; i += 256) {
        unsigned int p = pairs[start + i];
        int s = p & 0x1FFFF;
        int node = p >> 17;
        if (q < 3) {
            f16x4 u = *(const f16x4*)(xh + (size_t)s * 12 + q * 4);
            int* a = &acc[node][q * 4];
            atomicAdd(&a[0], __float2int_rn((float)u[0] * SCALE1));
            atomicAdd(&a[1], __float2int_rn((float)u[1] * SCALE1));
            atomicAdd(&a[2], __float2int_rn((float)u[2] * SCALE1));
            atomicAdd(&a[3], __float2int_rn((float)u[3] * SCALE1));
        } else {
            atomicAdd(&acc[node][12], 1);
        }
    }
    __syncthreads();

    if (t < 256) {
        int node = (b << 8) + t;
        if (node < N_NODES) deg_f[node] = (float)acc[t][12];
    }
    int base = b * 3072;  // 256 * 12
    for (int i = t; i < 3072; i += 1024) {
        int n = i / 12;
        int k = i - n * 12;
        int node = (b << 8) + n;
        if (node < N_NODES) {
            float invd = 1.0f / fmaxf((float)acc[n][12], 1.0f);
            agg1[base + i] = (float)acc[n][k] * (invd * (1.0f / SCALE1));
        }
    }
}

// ---------------- fused layer1 + dual projection via MFMA ----------------
__global__ __launch_bounds__(256) void layer1_proj_kernel(
        const float* __restrict__ x,
        const float* __restrict__ agg1,   // already the MEAN
        const float* __restrict__ W1l,
        const float* __restrict__ W1r,
        const float* __restrict__ b1,
        const float* __restrict__ W2l,
        const float* __restrict__ W2r,
        const float* __restrict__ b2,
        unsigned char* __restrict__ p8,
        float* __restrict__ r2) {
    __shared__ __attribute__((aligned(16))) _Float16 hA1[64][32];
    __shared__ __attribute__((aligned(16))) _Float16 WB1[64][32];
    __shared__ __attribute__((aligned(16))) _Float16 WB2[64][64];
    __shared__ __attribute__((aligned(16))) _Float16 hS[64][64];
    int t = threadIdx.x;
    int n0 = blockIdx.x * 64;

    for (int i = t; i < 64 * 32; i += 256) {
        int n = i >> 5, k = i & 31;
        float v = 0.0f;
        if (k < F_IN) v = W1l[k * F_H + n];
        else if (k < 2 * F_IN) v = W1r[(k - F_IN) * F_H + n];
        WB1[n][k] = (_Float16)v;
    }
    for (int i = t; i < 64 * 64; i += 256) {
        int n = i >> 6, k = i & 63;
        float v = (n < F_E) ? W2l[k * F_E + n] : W2r[k * F_E + (n - F_E)];
        WB2[n][k] = (_Float16)v;
    }
    for (int i = t; i < 64 * 32; i += 256) {
        int nl = i >> 5, k = i & 31;
        int n = n0 + nl;
        if (n >= N_NODES) n = N_NODES - 1;
        float v = 0.0f;
        if (k < F_IN) {
            v = agg1[(size_t)n * 12 + k];
        } else if (k < 2 * F_IN) {
            v = x[n * F_IN + (k - F_IN)];
        }
        hA1[nl][k] = (_Float16)v;
    }
    __syncthreads();

    int lane = t & 63;
    int wave = t >> 6;
    int col = lane & 15;
    int quad = lane >> 4;
    int mbase = wave * 16;

    f16x8 afrag = *(const f16x8*)&hA1[mbase + col][quad * 8];
    #pragma unroll
    for (int nt = 0; nt < 4; ++nt) {
        f16x8 bfrag = *(const f16x8*)&WB1[nt * 16 + col][quad * 8];
        float bias = b1[nt * 16 + col];
        f32x4 acc = {bias, bias, bias, bias};
        acc = __builtin_amdgcn_mfma_f32_16x16x32_f16(afrag, bfrag, acc, 0, 0, 0);
        #pragma unroll
        for (int r = 0; r < 4; ++r)
            hS[mbase + quad * 4 + r][nt * 16 + col] = (_Float16)fmaxf(acc[r], 0.0f);
    }
    __syncthreads();

    f16x8 a0 = *(const f16x8*)&hS[mbase + col][quad * 8];
    f16x8 a1 = *(const f16x8*)&hS[mbase + col][32 + quad * 8];
    #pragma unroll
    for (int nt = 0; nt < 4; ++nt) {
        f16x8 bf0 = *(const f16x8*)&WB2[nt * 16 + col][quad * 8];
        f16x8 bf1 = *(const f16x8*)&WB2[nt * 16 + col][32 + quad * 8];
        f32x4 acc;
        if (nt < 2) {
            acc = (f32x4){0.f, 0.f, 0.f, 0.f};
        } else {
            float bb = b2[(nt - 2) * 16 + col];
            acc = (f32x4){bb, bb, bb, bb};
        }
        acc = __builtin_amdgcn_mfma_f32_16x16x32_f16(a0, bf0, acc, 0, 0, 0);
        acc = __builtin_amdgcn_mfma_f32_16x16x32_f16(a1, bf1, acc, 0, 0, 0);
        #pragma unroll
        for (int r = 0; r < 4; ++r) {
            int node = n0 + mbase + quad * 4 + r;
            if (node < N_NODES) {
                if (nt < 2) {
                    __hip_fp8_e4m3 q((float)acc[r]);
                    p8[(size_t)node * F_E + nt * 16 + col] = (unsigned char)q.__x;
                } else {
                    r2[(size_t)node * F_E + (nt - 2) * 16 + col] = acc[r];
                }
            }
        }
    }
}

// decode 4 packed fp8 e4m3 -> 4 floats (hardware cvt on gfx950)
__device__ inline float4 fp8x4_to_f32(unsigned int w) {
#if defined(__gfx950__) || defined(__gfx942__) || defined(__gfx940__) || defined(__gfx941__)
    f32x2 lo = __builtin_amdgcn_cvt_pk_f32_fp8((int)w, false);
    f32x2 hi = __builtin_amdgcn_cvt_pk_f32_fp8((int)w, true);
    return make_float4(lo[0], lo[1], hi[0], hi[1]);
#else
    __hip_fp8_e4m3 a, b, c, d;
    a.__x = (__hip_fp8_storage_t)(w & 0xFF);
    b.__x = (__hip_fp8_storage_t)((w >> 8) & 0xFF);
    c.__x = (__hip_fp8_storage_t)((w >> 16) & 0xFF);
    d.__x = (__hip_fp8_storage_t)((w >> 24) & 0xFF);
    return make_float4((float)a, (float)b, (float)c, (float)d);
#endif
}

// ---------------- K4: pair-driven layer-2 aggregation, INT LDS atomics --------------
// 4 lanes per edge: lane q owns feature columns 8q..8q+7 and reads 8B of p8 (the
// 4 lanes together read one coalesced 32B row). Intra-edge lanes land on banks
// (node + 8q + j) — disjoint; inter-edge same-node collisions drop ~4x vs the
// one-edge-per-lane mapping. fp8 * 512 is exact; int sum is EXACT.
__global__ __launch_bounds__(1024) void layer2_kernel(const unsigned int* __restrict__ pairs,
                                                      const int* __restrict__ cursor,
                                                      const float* __restrict__ deg_f,
                                                      const unsigned char* __restrict__ p8,
                                                      const float* __restrict__ r2,
                                                      const float* __restrict__ Wc,
                                                      const float* __restrict__ bc,
                                                      float* __restrict__ emb,
                                                      float* __restrict__ logits) {
    __shared__ int acc[256][33];
    int b = blockIdx.x;
    int t = threadIdx.x;
    for (int i = t; i < 256 * 33; i += 1024) ((int*)acc)[i] = 0;
    __syncthreads();

    int start = b * CAP;
    int cntAll = cursor[b];
    int q = t & 3;
    for (int i = (t >> 2); i < cntAll; i += 256) {
        unsigned int p = pairs[start + i];
        int s = p & 0x1FFFF;
        int node = p >> 17;
        uint2 w = *(const uint2*)(p8 + (size_t)s * 32 + q * 8);
        float4 va = fp8x4_to_f32(w.x);
        float4 vb = fp8x4_to_f32(w.y);
        int* a = &acc[node][q * 8];
        atomicAdd(&a[0], (int)(va.x * SCALE2));
        atomicAdd(&a[1], (int)(va.y * SCALE2));
        atomicAdd(&a[2], (int)(va.z * SCALE2));
        atomicAdd(&a[3], (int)(va.w * SCALE2));
        atomicAdd(&a[4], (int)(vb.x * SCALE2));
        atomicAdd(&a[5], (int)(vb.y * SCALE2));
        atomicAdd(&a[6], (int)(vb.z * SCALE2));
        atomicAdd(&a[7], (int)(vb.w * SCALE2));
    }
    __syncthreads();

    // epilogue: 4 threads per node, 8 features each
    int n = t >> 2;
    int node = (b << 8) + n;
    if (node < N_NODES) {
        float sc = (1.0f / SCALE2) / fmaxf(deg_f[node], 1.0f);
        const float* rr = r2 + (size_t)node * F_E + 8 * q;
        float e[8];
        #pragma unroll
        for (int j = 0; j < 8; ++j)
            e[j] = fmaxf((float)acc[n][8 * q + j] * sc + rr[j], 0.0f);
        float4* ep = (float4*)(emb + (size_t)node * F_E + 8 * q);
        ep[0] = make_float4(e[0], e[1], e[2], e[3]);
        ep[1] = make_float4(e[4], e[5], e[6], e[7]);
        float c0 = 0.f, c1 = 0.f, c2 = 0.f;
        #pragma unroll
        for (int j = 0; j < 8; ++j) {
            const float* w = Wc + (8 * q + j) * 3;
            c0 += e[j] * w[0];
            c1 += e[j] * w[1];
            c2 += e[j] * w[2];
        }
        c0 += __shfl_xor(c0, 1); c1 += __shfl_xor(c1, 1); c2 += __shfl_xor(c2, 1);
        c0 += __shfl_xor(c0, 2); c1 += __shfl_xor(c1, 2); c2 += __shfl_xor(c2, 2);
        if (q == 0) {
            logits[(size_t)node * 3 + 0] = c0 + bc[0];
            logits[(size_t)node * 3 + 1] = c1 + bc[1];
            logits[(size_t)node * 3 + 2] = c2 + bc[2];
        }
    }
}

extern "C" void kernel_launch(void* const* d_in, const int* in_sizes, int n_in,
                              void* d_out, int out_size, void* d_ws, size_t ws_size,
                              hipStream_t stream) {
    const float* x   = (const float*)d_in[0];
    const int*   ei  = (const int*)d_in[1];
    const float* W1l = (const float*)d_in[2];
    const float* W1r = (const float*)d_in[3];
    const float* b1  = (const float*)d_in[4];
    const float* W2l = (const float*)d_in[5];
    const float* W2r = (const float*)d_in[6];
    const float* b2  = (const float*)d_in[7];
    const float* Wc  = (const float*)d_in[8];
    const float* bc  = (const float*)d_in[9];

    const int* src = ei;
    const int* dst = ei + E_EDGES;

    float* out    = (float*)d_out;
    float* logits = out;
    float* emb    = out + (size_t)N_NODES * 3;

    // ws layout (4B units):
    //   deg_f (N) | cursor(512) | pairs (BUCKETS*CAP) | r2 (32N) | p8 (8N)
    //   | xh (6N: [N][12] halves) | agg1 (12N)
    int* ws_i     = (int*)d_ws;
    float* deg_f  = (float*)ws_i;
    int* cursor   = ws_i + N_NODES;
    unsigned int* pairs = (unsigned int*)(cursor + 512);
    int* base2    = (int*)(pairs + (size_t)BUCKETS * CAP);
    float* r2     = (float*)base2;                                       // 32N
    unsigned char* p8 = (unsigned char*)(base2 + (size_t)32 * N_NODES);  // 8N units
    _Float16* xh  = (_Float16*)(base2 + (size_t)40 * N_NODES);           // 6N units
    float* agg1   = (float*)(base2 + (size_t)46 * N_NODES);              // 12N

    hipMemsetAsync(cursor, 0, 512 * sizeof(int), stream);

    binA_kernel<<<NWG_A, 1024, 0, stream>>>(x, src, dst, cursor, pairs, xh);
    agg1_kernel<<<BUCKETS, 1024, 0, stream>>>(pairs, cursor, xh, deg_f, agg1);
    layer1_proj_kernel<<<(N_NODES + 63) / 64, 256, 0, stream>>>(
        x, agg1, W1l, W1r, b1, W2l, W2r, b2, p8, r2);
    layer2_kernel<<<BUCKETS, 1024, 0, stream>>>(
        pairs, cursor, deg_f, p8, r2, Wc, bc, emb, logits);
}

// Round 5
// 183.363 us; speedup vs baseline: 6.0226x; 1.1885x over previous
//
#include <hip/hip_runtime.h>
#include <hip/hip_fp16.h>
#include <hip/hip_fp8.h>

#define N_NODES 100000
#define E_EDGES 3200000
#define F_IN 11
#define F_H 64
#define F_E 32

#define BUCKETS ((N_NODES + 255) >> 8)   // 391 coarse buckets (dst>>8)
#define CAP 9216                         // slack bucket capacity (mean ~8184, +11 sigma)
#define CHUNK_A 12288
#define NWG_A ((E_EDGES + CHUNK_A - 1) / CHUNK_A)  // 261
#define EPT 12                           // binA edges per thread (CHUNK_A / 1024)

// fixed-point scales for integer LDS accumulation
#define SCALE1 32768.0f                  // layer-1 f16 features (rounding ~1.5e-5/add)
#define SCALE2 512.0f                    // layer-2 fp8 values: EXACT (fp8 * 512 is integer)

typedef __attribute__((ext_vector_type(8))) _Float16 f16x8;
typedef __attribute__((ext_vector_type(4))) _Float16 f16x4;
typedef __attribute__((ext_vector_type(4))) float f32x4;
typedef __attribute__((ext_vector_type(2))) float f32x2;

// ---------------- binA: hist -> wave0 shuffle-scan -> reservation -> LDS stage ->
// coalesced pairs writeout via bucket-id side array (no binary search).
// (+ fused x -> fp16 conversion prologue; xh consumed only by the NEXT kernel)
__global__ __launch_bounds__(1024) void binA_kernel(const float* __restrict__ x,
                                                    const int* __restrict__ src,
                                                    const int* __restrict__ dst,
                                                    int* __restrict__ cursor,
                                                    unsigned int* __restrict__ pairs,
                                                    _Float16* __restrict__ xh) {
    __shared__ int lh[BUCKETS];
    __shared__ int lstart[BUCKETS];
    __shared__ int lcur[BUCKETS];
    __shared__ int gbase[BUCKETS];
    __shared__ unsigned int stage[CHUNK_A];
    __shared__ unsigned short sbuck[CHUNK_A];
    int t = threadIdx.x;

    // fused convert: x [N][11] f32 -> xh [N][12] f16 (zero-padded)
    for (int i = blockIdx.x * 1024 + t; i < N_NODES * 12; i += NWG_A * 1024) {
        int n = i / 12;
        int f = i - n * 12;
        xh[i] = (_Float16)((f < F_IN) ? x[n * F_IN + f] : 0.0f);
    }

    for (int i = t; i < BUCKETS; i += 1024) lh[i] = 0;
    __syncthreads();

    int e0 = blockIdx.x * CHUNK_A;
    int e1 = min(e0 + CHUNK_A, E_EDGES);

    unsigned int pv[EPT];
    int pb[EPT];
    int cnt = 0;
    for (int i = e0 + t; i < e1; i += 1024) {
        int d = dst[i];
        int b = d >> 8;
        pv[cnt] = (unsigned int)src[i] | (((unsigned int)(d & 255)) << 17);
        pb[cnt] = b;
        ++cnt;
        atomicAdd(&lh[b], 1);
    }
    __syncthreads();

    // exclusive scan of lh into lstart: wave 0 only, 7 chunks of 64 via shuffles
    if (t < 64) {
        int carry = 0;
        for (int c = 0; c < 7; ++c) {
            int idx = c * 64 + t;
            int hv = (idx < BUCKETS) ? lh[idx] : 0;
            int v = hv;
            #pragma unroll
            for (int off = 1; off < 64; off <<= 1) {
                int u = __shfl_up(v, off);
                if (t >= off) v += u;
            }
            if (idx < BUCKETS) lstart[idx] = carry + v - hv;
            carry += __shfl(v, 63);
        }
    }
    __syncthreads();

    // per-bucket global reservation + init claim counters
    for (int i = t; i < BUCKETS; i += 1024) {
        lcur[i] = lstart[i];
        int c = lh[i];
        if (c > 0) gbase[i] = i * CAP + atomicAdd(&cursor[i], c);
    }
    __syncthreads();

    // scatter into stage, record bucket id per slot
    for (int k = 0; k < cnt; ++k) {
        int b = pb[k];
        int pos = atomicAdd(&lcur[b], 1);
        stage[pos] = pv[k];
        sbuck[pos] = (unsigned short)b;
    }
    __syncthreads();

    // coalesced writeout: consecutive i within a bucket -> consecutive global addrs
    int total = e1 - e0;
    for (int i = t; i < total; i += 1024) {
        int b = sbuck[i];
        pairs[gbase[b] + (i - lstart[b])] = stage[i];
    }
}

// ---------------- K2: fused layer-1 aggregation + dual MFMA projection --------------
// Per bucket (256 nodes): pair-driven INT LDS atomic aggregation (4 lanes/edge),
// then build the A-tile in LDS and run both layer-1 and layer-2 projections with
// 16 waves. Outputs p8 (fp8 h1) and r2 (W2r-side residual) for layer 2.
__global__ __launch_bounds__(1024) void aggproj_kernel(
        const unsigned int* __restrict__ pairs,
        const int* __restrict__ cursor,
        const _Float16* __restrict__ xh,
        const float* __restrict__ x,
        const float* __restrict__ W1l,
        const float* __restrict__ W1r,
        const float* __restrict__ b1,
        const float* __restrict__ W2l,
        const float* __restrict__ W2r,
        const float* __restrict__ b2,
        float* __restrict__ deg_f,
        unsigned char* __restrict__ p8,
        float* __restrict__ r2) {
    __shared__ int acc[256][13];
    __shared__ __attribute__((aligned(16))) _Float16 hA1[256][32];
    __shared__ __attribute__((aligned(16))) _Float16 hS[256][64];
    __shared__ __attribute__((aligned(16))) _Float16 WB1[64][32];
    __shared__ __attribute__((aligned(16))) _Float16 WB2[64][64];
    int b = blockIdx.x;
    int t = threadIdx.x;

    for (int i = t; i < 256 * 13; i += 1024) ((int*)acc)[i] = 0;
    for (int i = t; i < 64 * 32; i += 1024) {
        int n = i >> 5, k = i & 31;
        float v = 0.0f;
        if (k < F_IN) v = W1l[k * F_H + n];
        else if (k < 2 * F_IN) v = W1r[(k - F_IN) * F_H + n];
        WB1[n][k] = (_Float16)v;
    }
    for (int i = t; i < 64 * 64; i += 1024) {
        int n = i >> 6, k = i & 63;
        float v = (n < F_E) ? W2l[k * F_E + n] : W2r[k * F_E + (n - F_E)];
        WB2[n][k] = (_Float16)v;
    }
    __syncthreads();

    // pair-driven aggregation: 4 lanes per edge (3 feature lanes + 1 degree lane)
    int start = b * CAP;
    int cntAll = cursor[b];
    int q = t & 3;
    for (int i = (t >> 2); i < cntAll; i += 256) {
        unsigned int p = pairs[start + i];
        int s = p & 0x1FFFF;
        int node = p >> 17;
        if (q < 3) {
            f16x4 u = *(const f16x4*)(xh + (size_t)s * 12 + q * 4);
            int* a = &acc[node][q * 4];
            atomicAdd(&a[0], __float2int_rn((float)u[0] * SCALE1));
            atomicAdd(&a[1], __float2int_rn((float)u[1] * SCALE1));
            atomicAdd(&a[2], __float2int_rn((float)u[2] * SCALE1));
            atomicAdd(&a[3], __float2int_rn((float)u[3] * SCALE1));
        } else {
            atomicAdd(&acc[node][12], 1);
        }
    }
    __syncthreads();

    // build A-tile: [mean_agg (11) | x (11) | 0-pad], and export degree
    if (t < 256) {
        int node = (b << 8) + t;
        if (node < N_NODES) deg_f[node] = (float)acc[t][12];
    }
    for (int i = t; i < 256 * 32; i += 1024) {
        int nl = i >> 5, k = i & 31;
        int node = (b << 8) + nl;
        int nc = (node < N_NODES) ? node : (N_NODES - 1);
        float v = 0.0f;
        if (k < F_IN) {
            float invd = 1.0f / fmaxf((float)acc[nl][12], 1.0f);
            v = (float)acc[nl][k] * (invd * (1.0f / SCALE1));
        } else if (k < 2 * F_IN) {
            v = x[nc * F_IN + (k - F_IN)];
        }
        hA1[nl][k] = (_Float16)v;
    }
    __syncthreads();

    int lane = t & 63;
    int wave = t >> 6;        // 16 waves, wave w owns rows w*16..w*16+15
    int col = lane & 15;
    int quad = lane >> 4;
    int mbase = wave * 16;

    f16x8 afrag = *(const f16x8*)&hA1[mbase + col][quad * 8];
    #pragma unroll
    for (int nt = 0; nt < 4; ++nt) {
        f16x8 bfrag = *(const f16x8*)&WB1[nt * 16 + col][quad * 8];
        float bias = b1[nt * 16 + col];
        f32x4 a = {bias, bias, bias, bias};
        a = __builtin_amdgcn_mfma_f32_16x16x32_f16(afrag, bfrag, a, 0, 0, 0);
        #pragma unroll
        for (int r = 0; r < 4; ++r)
            hS[mbase + quad * 4 + r][nt * 16 + col] = (_Float16)fmaxf(a[r], 0.0f);
    }
    __syncthreads();

    f16x8 a0 = *(const f16x8*)&hS[mbase + col][quad * 8];
    f16x8 a1 = *(const f16x8*)&hS[mbase + col][32 + quad * 8];
    #pragma unroll
    for (int nt = 0; nt < 4; ++nt) {
        f16x8 bf0 = *(const f16x8*)&WB2[nt * 16 + col][quad * 8];
        f16x8 bf1 = *(const f16x8*)&WB2[nt * 16 + col][32 + quad * 8];
        f32x4 a;
        if (nt < 2) {
            a = (f32x4){0.f, 0.f, 0.f, 0.f};
        } else {
            float bb = b2[(nt - 2) * 16 + col];
            a = (f32x4){bb, bb, bb, bb};
        }
        a = __builtin_amdgcn_mfma_f32_16x16x32_f16(a0, bf0, a, 0, 0, 0);
        a = __builtin_amdgcn_mfma_f32_16x16x32_f16(a1, bf1, a, 0, 0, 0);
        #pragma unroll
        for (int r = 0; r < 4; ++r) {
            int node = (b << 8) + mbase + quad * 4 + r;
            if (node < N_NODES) {
                if (nt < 2) {
                    __hip_fp8_e4m3 qv((float)a[r]);
                    p8[(size_t)node * F_E + nt * 16 + col] = (unsigned char)qv.__x;
                } else {
                    r2[(size_t)node * F_E + (nt - 2) * 16 + col] = a[r];
                }
            }
        }
    }
}

// decode 4 packed fp8 e4m3 -> 4 floats (hardware cvt on gfx950)
__device__ inline float4 fp8x4_to_f32(unsigned int w) {
#if defined(__gfx950__) || defined(__gfx942__) || defined(__gfx940__) || defined(__gfx941__)
    f32x2 lo = __builtin_amdgcn_cvt_pk_f32_fp8((int)w, false);
    f32x2 hi = __builtin_amdgcn_cvt_pk_f32_fp8((int)w, true);
    return make_float4(lo[0], lo[1], hi[0], hi[1]);
#else
    __hip_fp8_e4m3 a, b, c, d;
    a.__x = (__hip_fp8_storage_t)(w & 0xFF);
    b.__x = (__hip_fp8_storage_t)((w >> 8) & 0xFF);
    c.__x = (__hip_fp8_storage_t)((w >> 16) & 0xFF);
    d.__x = (__hip_fp8_storage_t)((w >> 24) & 0xFF);
    return make_float4((float)a, (float)b, (float)c, (float)d);
#endif
}

// ---------------- K3: pair-driven layer-2 aggregation, INT LDS atomics --------------
// 4 lanes per edge; TWO accumulator copies selected by edge parity halve
// same-address RMW serialization. fp8 * 512 is exact; int sum is EXACT.
__global__ __launch_bounds__(1024) void layer2_kernel(const unsigned int* __restrict__ pairs,
                                                      const int* __restrict__ cursor,
                                                      const float* __restrict__ deg_f,
                                                      const unsigned char* __restrict__ p8,
                                                      const float* __restrict__ r2,
                                                      const float* __restrict__ Wc,
                                                      const float* __restrict__ bc,
                                                      float* __restrict__ emb,
                                                      float* __restrict__ logits) {
    __shared__ int acc[2][256][33];
    int b = blockIdx.x;
    int t = threadIdx.x;
    for (int i = t; i < 2 * 256 * 33; i += 1024) ((int*)acc)[i] = 0;
    __syncthreads();

    int start = b * CAP;
    int cntAll = cursor[b];
    int q = t & 3;
    int cp = (t >> 2) & 1;
    for (int i = (t >> 2); i < cntAll; i += 256) {
        unsigned int p = pairs[start + i];
        int s = p & 0x1FFFF;
        int node = p >> 17;
        uint2 w = *(const uint2*)(p8 + (size_t)s * 32 + q * 8);
        float4 va = fp8x4_to_f32(w.x);
        float4 vb = fp8x4_to_f32(w.y);
        int* a = &acc[cp][node][q * 8];
        atomicAdd(&a[0], (int)(va.x * SCALE2));
        atomicAdd(&a[1], (int)(va.y * SCALE2));
        atomicAdd(&a[2], (int)(va.z * SCALE2));
        atomicAdd(&a[3], (int)(va.w * SCALE2));
        atomicAdd(&a[4], (int)(vb.x * SCALE2));
        atomicAdd(&a[5], (int)(vb.y * SCALE2));
        atomicAdd(&a[6], (int)(vb.z * SCALE2));
        atomicAdd(&a[7], (int)(vb.w * SCALE2));
    }
    __syncthreads();

    // merge copy 1 into copy 0
    for (int i = t; i < 256 * 33; i += 1024) ((int*)acc[0])[i] += ((int*)acc[1])[i];
    __syncthreads();

    // epilogue: 4 threads per node, 8 features each
    int n = t >> 2;
    int node = (b << 8) + n;
    if (node < N_NODES) {
        float sc = (1.0f / SCALE2) / fmaxf(deg_f[node], 1.0f);
        const float* rr = r2 + (size_t)node * F_E + 8 * q;
        float e[8];
        #pragma unroll
        for (int j = 0; j < 8; ++j)
            e[j] = fmaxf((float)acc[0][n][8 * q + j] * sc + rr[j], 0.0f);
        float4* ep = (float4*)(emb + (size_t)node * F_E + 8 * q);
        ep[0] = make_float4(e[0], e[1], e[2], e[3]);
        ep[1] = make_float4(e[4], e[5], e[6], e[7]);
        float c0 = 0.f, c1 = 0.f, c2 = 0.f;
        #pragma unroll
        for (int j = 0; j < 8; ++j) {
            const float* w = Wc + (8 * q + j) * 3;
            c0 += e[j] * w[0];
            c1 += e[j] * w[1];
            c2 += e[j] * w[2];
        }
        c0 += __shfl_xor(c0, 1); c1 += __shfl_xor(c1, 1); c2 += __shfl_xor(c2, 1);
        c0 += __shfl_xor(c0, 2); c1 += __shfl_xor(c1, 2); c2 += __shfl_xor(c2, 2);
        if (q == 0) {
            logits[(size_t)node * 3 + 0] = c0 + bc[0];
            logits[(size_t)node * 3 + 1] = c1 + bc[1];
            logits[(size_t)node * 3 + 2] = c2 + bc[2];
        }
    }
}

extern "C" void kernel_launch(void* const* d_in, const int* in_sizes, int n_in,
                              void* d_out, int out_size, void* d_ws, size_t ws_size,
                              hipStream_t stream) {
    const float* x   = (const float*)d_in[0];
    const int*   ei  = (const int*)d_in[1];
    const float* W1l = (const float*)d_in[2];
    const float* W1r = (const float*)d_in[3];
    const float* b1  = (const float*)d_in[4];
    const float* W2l = (const float*)d_in[5];
    const float* W2r = (const float*)d_in[6];
    const float* b2  = (const float*)d_in[7];
    const float* Wc  = (const float*)d_in[8];
    const float* bc  = (const float*)d_in[9];

    const int* src = ei;
    const int* dst = ei + E_EDGES;

    float* out    = (float*)d_out;
    float* logits = out;
    float* emb    = out + (size_t)N_NODES * 3;

    // ws layout (4B units):
    //   deg_f (N) | cursor(512) | pairs (BUCKETS*CAP) | r2 (32N) | p8 (8N)
    //   | xh (6N: [N][12] halves)
    int* ws_i     = (int*)d_ws;
    float* deg_f  = (float*)ws_i;
    int* cursor   = ws_i + N_NODES;
    unsigned int* pairs = (unsigned int*)(cursor + 512);
    int* base2    = (int*)(pairs + (size_t)BUCKETS * CAP);
    float* r2     = (float*)base2;                                       // 32N
    unsigned char* p8 = (unsigned char*)(base2 + (size_t)32 * N_NODES);  // 8N units
    _Float16* xh  = (_Float16*)(base2 + (size_t)40 * N_NODES);           // 6N units

    hipMemsetAsync(cursor, 0, 512 * sizeof(int), stream);

    binA_kernel<<<NWG_A, 1024, 0, stream>>>(x, src, dst, cursor, pairs, xh);
    aggproj_kernel<<<BUCKETS, 1024, 0, stream>>>(
        pairs, cursor, xh, x, W1l, W1r, b1, W2l, W2r, b2, deg_f, p8, r2);
    layer2_kernel<<<BUCKETS, 1024, 0, stream>>>(
        pairs, cursor, deg_f, p8, r2, Wc, bc, emb, logits);
}

// Round 7
// 172.218 us; speedup vs baseline: 6.4123x; 1.0647x over previous
//
#include <hip/hip_runtime.h>
#include <hip/hip_fp16.h>
#include <hip/hip_fp8.h>

#define N_NODES 100000
#define E_EDGES 3200000
#define F_IN 11
#define F_H 64
#define F_E 32

#define BSZ 196                          // nodes per bucket
#define NB 511                           // ceil(N_NODES / BSZ) -> ~2 blocks/CU, balanced
#define CAP 7168                         // bucket capacity (mean ~6272, +11 sigma)
#define CHUNK_A 12500
#define NWG_A 256                        // 256 * 12500 == E_EDGES exactly; 1 block/CU
#define EPTA 13                          // ceil(CHUNK_A / 1024)

// fixed-point scales for integer LDS accumulation
#define SCALE1 32768.0f                  // layer-1 f16 features (rounding ~1.5e-5/add)
#define SCALE2 512.0f                    // layer-2 fp8 values: EXACT (fp8 * 512 is integer)

typedef __attribute__((ext_vector_type(8))) _Float16 f16x8;
typedef __attribute__((ext_vector_type(4))) _Float16 f16x4;
typedef __attribute__((ext_vector_type(4))) float f32x4;
typedef __attribute__((ext_vector_type(2))) float f32x2;

// ---------------- binA: hist -> wave0 shuffle-scan -> reservation -> LDS stage ->
// coalesced pairs writeout via bucket-id side array (no binary search).
// (+ fused x -> fp16 conversion prologue; xh consumed only by the NEXT kernel)
__global__ __launch_bounds__(1024) void binA_kernel(const float* __restrict__ x,
                                                    const int* __restrict__ src,
                                                    const int* __restrict__ dst,
                                                    int* __restrict__ cursor,
                                                    unsigned int* __restrict__ pairs,
                                                    _Float16* __restrict__ xh) {
    __shared__ int lh[NB];
    __shared__ int lstart[NB];
    __shared__ int lcur[NB];
    __shared__ int gbase[NB];
    __shared__ unsigned int stage[CHUNK_A];
    __shared__ unsigned short sbuck[CHUNK_A];
    int t = threadIdx.x;

    // fused convert: x [N][11] f32 -> xh [N][12] f16 (zero-padded)
    for (int i = blockIdx.x * 1024 + t; i < N_NODES * 12; i += NWG_A * 1024) {
        int n = i / 12;
        int f = i - n * 12;
        xh[i] = (_Float16)((f < F_IN) ? x[n * F_IN + f] : 0.0f);
    }

    for (int i = t; i < NB; i += 1024) lh[i] = 0;
    __syncthreads();

    int e0 = blockIdx.x * CHUNK_A;
    int e1 = min(e0 + CHUNK_A, E_EDGES);

    unsigned int pv[EPTA];
    int pb[EPTA];
    int cnt = 0;
    for (int i = e0 + t; i < e1; i += 1024) {
        int d = dst[i];
        int b = d / BSZ;                 // constant divide -> magic mul
        int nib = d - b * BSZ;           // 0..195, fits in 8 bits
        pv[cnt] = (unsigned int)src[i] | (((unsigned int)nib) << 17);
        pb[cnt] = b;
        ++cnt;
        atomicAdd(&lh[b], 1);
    }
    __syncthreads();

    // exclusive scan of lh into lstart: wave 0 only, 8 chunks of 64 via shuffles
    if (t < 64) {
        int carry = 0;
        for (int c = 0; c < 8; ++c) {
            int idx = c * 64 + t;
            int hv = (idx < NB) ? lh[idx] : 0;
            int v = hv;
            #pragma unroll
            for (int off = 1; off < 64; off <<= 1) {
                int u = __shfl_up(v, off);
                if (t >= off) v += u;
            }
            if (idx < NB) lstart[idx] = carry + v - hv;
            carry += __shfl(v, 63);
        }
    }
    __syncthreads();

    // per-bucket global reservation + init claim counters
    for (int i = t; i < NB; i += 1024) {
        lcur[i] = lstart[i];
        int c = lh[i];
        if (c > 0) gbase[i] = i * CAP + atomicAdd(&cursor[i], c);
    }
    __syncthreads();

    // scatter into stage, record bucket id per slot
    for (int k = 0; k < cnt; ++k) {
        int b = pb[k];
        int pos = atomicAdd(&lcur[b], 1);
        stage[pos] = pv[k];
        sbuck[pos] = (unsigned short)b;
    }
    __syncthreads();

    // coalesced writeout: consecutive i within a bucket -> consecutive global addrs
    int total = e1 - e0;
    for (int i = t; i < total; i += 1024) {
        int b = sbuck[i];
        pairs[gbase[b] + (i - lstart[b])] = stage[i];
    }
}

// ---------------- K2: fused layer-1 aggregation + dual MFMA projection --------------
// Per bucket (196 nodes): pair-driven INT LDS atomic aggregation (4 lanes/edge,
// 2x unrolled for MLP), then build the A-tile in LDS and run both projections.
__global__ __launch_bounds__(1024) void aggproj_kernel(
        const unsigned int* __restrict__ pairs,
        const int* __restrict__ cursor,
        const _Float16* __restrict__ xh,
        const float* __restrict__ x,
        const float* __restrict__ W1l,
        const float* __restrict__ W1r,
        const float* __restrict__ b1,
        const float* __restrict__ W2l,
        const float* __restrict__ W2r,
        const float* __restrict__ b2,
        float* __restrict__ deg_f,
        unsigned char* __restrict__ p8,
        float* __restrict__ r2) {
    __shared__ int acc[256][13];
    __shared__ __attribute__((aligned(16))) _Float16 hA1[256][32];
    __shared__ __attribute__((aligned(16))) _Float16 hS[256][64];
    __shared__ __attribute__((aligned(16))) _Float16 WB1[64][32];
    __shared__ __attribute__((aligned(16))) _Float16 WB2[64][64];
    int b = blockIdx.x;
    int t = threadIdx.x;

    for (int i = t; i < 256 * 13; i += 1024) ((int*)acc)[i] = 0;
    for (int i = t; i < 64 * 32; i += 1024) {
        int n = i >> 5, k = i & 31;
        float v = 0.0f;
        if (k < F_IN) v = W1l[k * F_H + n];
        else if (k < 2 * F_IN) v = W1r[(k - F_IN) * F_H + n];
        WB1[n][k] = (_Float16)v;
    }
    for (int i = t; i < 64 * 64; i += 1024) {
        int n = i >> 6, k = i & 63;
        float v = (n < F_E) ? W2l[k * F_E + n] : W2r[k * F_E + (n - F_E)];
        WB2[n][k] = (_Float16)v;
    }
    __syncthreads();

    // pair-driven aggregation: 4 lanes/edge, 2 edges/iteration for MLP
    int start = b * CAP;
    int cntAll = cursor[b];
    int q = t & 3;
    for (int i = (t >> 2); i < cntAll; i += 512) {
        unsigned int p0 = pairs[start + i];
        bool h1 = (i + 256) < cntAll;
        unsigned int p1 = h1 ? pairs[start + i + 256] : p0;
        int s0 = p0 & 0x1FFFF, d0 = p0 >> 17;
        int s1 = p1 & 0x1FFFF, d1 = p1 >> 17;
        if (q < 3) {
            f16x4 u0 = *(const f16x4*)(xh + (size_t)s0 * 12 + q * 4);
            f16x4 u1 = *(const f16x4*)(xh + (size_t)s1 * 12 + q * 4);
            int* a0 = &acc[d0][q * 4];
            atomicAdd(&a0[0], __float2int_rn((float)u0[0] * SCALE1));
            atomicAdd(&a0[1], __float2int_rn((float)u0[1] * SCALE1));
            atomicAdd(&a0[2], __float2int_rn((float)u0[2] * SCALE1));
            atomicAdd(&a0[3], __float2int_rn((float)u0[3] * SCALE1));
            if (h1) {
                int* a1 = &acc[d1][q * 4];
                atomicAdd(&a1[0], __float2int_rn((float)u1[0] * SCALE1));
                atomicAdd(&a1[1], __float2int_rn((float)u1[1] * SCALE1));
                atomicAdd(&a1[2], __float2int_rn((float)u1[2] * SCALE1));
                atomicAdd(&a1[3], __float2int_rn((float)u1[3] * SCALE1));
            }
        } else {
            atomicAdd(&acc[d0][12], 1);
            if (h1) atomicAdd(&acc[d1][12], 1);
        }
    }
    __syncthreads();

    // build A-tile: [mean_agg (11) | x (11) | 0-pad], and export degree
    if (t < BSZ) {
        int node = b * BSZ + t;
        if (node < N_NODES) deg_f[node] = (float)acc[t][12];
    }
    for (int i = t; i < 256 * 32; i += 1024) {
        int nl = i >> 5, k = i & 31;
        int node = b * BSZ + nl;
        float v = 0.0f;
        if (nl < BSZ && node < N_NODES) {
            if (k < F_IN) {
                float invd = 1.0f / fmaxf((float)acc[nl][12], 1.0f);
                v = (float)acc[nl][k] * (invd * (1.0f / SCALE1));
            } else if (k < 2 * F_IN) {
                v = x[node * F_IN + (k - F_IN)];
            }
        }
        hA1[nl][k] = (_Float16)v;
    }
    __syncthreads();

    int lane = t & 63;
    int wave = t >> 6;        // 16 waves, wave w owns rows w*16..w*16+15
    int col = lane & 15;
    int quad = lane >> 4;
    int mbase = wave * 16;

    f16x8 afrag = *(const f16x8*)&hA1[mbase + col][quad * 8];
    #pragma unroll
    for (int nt = 0; nt < 4; ++nt) {
        f16x8 bfrag = *(const f16x8*)&WB1[nt * 16 + col][quad * 8];
        float bias = b1[nt * 16 + col];
        f32x4 a = {bias, bias, bias, bias};
        a = __builtin_amdgcn_mfma_f32_16x16x32_f16(afrag, bfrag, a, 0, 0, 0);
        #pragma unroll
        for (int r = 0; r < 4; ++r)
            hS[mbase + quad * 4 + r][nt * 16 + col] = (_Float16)fmaxf(a[r], 0.0f);
    }
    __syncthreads();

    f16x8 a0 = *(const f16x8*)&hS[mbase + col][quad * 8];
    f16x8 a1 = *(const f16x8*)&hS[mbase + col][32 + quad * 8];
    #pragma unroll
    for (int nt = 0; nt < 4; ++nt) {
        f16x8 bf0 = *(const f16x8*)&WB2[nt * 16 + col][quad * 8];
        f16x8 bf1 = *(const f16x8*)&WB2[nt * 16 + col][32 + quad * 8];
        f32x4 a;
        if (nt < 2) {
            a = (f32x4){0.f, 0.f, 0.f, 0.f};
        } else {
            float bb = b2[(nt - 2) * 16 + col];
            a = (f32x4){bb, bb, bb, bb};
        }
        a = __builtin_amdgcn_mfma_f32_16x16x32_f16(a0, bf0, a, 0, 0, 0);
        a = __builtin_amdgcn_mfma_f32_16x16x32_f16(a1, bf1, a, 0, 0, 0);
        #pragma unroll
        for (int r = 0; r < 4; ++r) {
            int row = mbase + quad * 4 + r;
            int node = b * BSZ + row;
            if (row < BSZ && node < N_NODES) {
                if (nt < 2) {
                    __hip_fp8_e4m3 qv((float)a[r]);
                    p8[(size_t)node * F_E + nt * 16 + col] = (unsigned char)qv.__x;
                } else {
                    r2[(size_t)node * F_E + (nt - 2) * 16 + col] = a[r];
                }
            }
        }
    }
}

// decode 4 packed fp8 e4m3 -> 4 floats (hardware cvt on gfx950)
__device__ inline float4 fp8x4_to_f32(unsigned int w) {
#if defined(__gfx950__) || defined(__gfx942__) || defined(__gfx940__) || defined(__gfx941__)
    f32x2 lo = __builtin_amdgcn_cvt_pk_f32_fp8((int)w, false);
    f32x2 hi = __builtin_amdgcn_cvt_pk_f32_fp8((int)w, true);
    return make_float4(lo[0], lo[1], hi[0], hi[1]);
#else
    __hip_fp8_e4m3 a, b, c, d;
    a.__x = (__hip_fp8_storage_t)(w & 0xFF);
    b.__x = (__hip_fp8_storage_t)((w >> 8) & 0xFF);
    c.__x = (__hip_fp8_storage_t)((w >> 16) & 0xFF);
    d.__x = (__hip_fp8_storage_t)((w >> 24) & 0xFF);
    return make_float4((float)a, (float)b, (float)c, (float)d);
#endif
}

// ---------------- K3: pair-driven layer-2 aggregation, INT LDS atomics --------------
// 4 lanes/edge, 2 edges/iteration; TWO accumulator copies (edge parity) halve
// same-address RMW serialization. fp8 * 512 is exact; int sum is EXACT.
__global__ __launch_bounds__(1024) void layer2_kernel(const unsigned int* __restrict__ pairs,
                                                      const int* __restrict__ cursor,
                                                      const float* __restrict__ deg_f,
                                                      const unsigned char* __restrict__ p8,
                                                      const float* __restrict__ r2,
                                                      const float* __restrict__ Wc,
                                                      const float* __restrict__ bc,
                                                      float* __restrict__ emb,
                                                      float* __restrict__ logits) {
    __shared__ int acc[2][256][33];
    int b = blockIdx.x;
    int t = threadIdx.x;
    for (int i = t; i < 2 * 256 * 33; i += 1024) ((int*)acc)[i] = 0;
    __syncthreads();

    int start = b * CAP;
    int cntAll = cursor[b];
    int q = t & 3;
    int cp = (t >> 2) & 1;
    for (int i = (t >> 2); i < cntAll; i += 512) {
        unsigned int p0 = pairs[start + i];
        bool h1 = (i + 256) < cntAll;
        unsigned int p1 = h1 ? pairs[start + i + 256] : p0;
        int s0 = p0 & 0x1FFFF, d0 = p0 >> 17;
        int s1 = p1 & 0x1FFFF, d1 = p1 >> 17;
        uint2 w0 = *(const uint2*)(p8 + (size_t)s0 * 32 + q * 8);
        uint2 w1 = *(const uint2*)(p8 + (size_t)s1 * 32 + q * 8);
        {
            float4 va = fp8x4_to_f32(w0.x);
            float4 vb = fp8x4_to_f32(w0.y);
            int* a = &acc[cp][d0][q * 8];
            atomicAdd(&a[0], (int)(va.x * SCALE2));
            atomicAdd(&a[1], (int)(va.y * SCALE2));
            atomicAdd(&a[2], (int)(va.z * SCALE2));
            atomicAdd(&a[3], (int)(va.w * SCALE2));
            atomicAdd(&a[4], (int)(vb.x * SCALE2));
            atomicAdd(&a[5], (int)(vb.y * SCALE2));
            atomicAdd(&a[6], (int)(vb.z * SCALE2));
            atomicAdd(&a[7], (int)(vb.w * SCALE2));
        }
        if (h1) {
            float4 va = fp8x4_to_f32(w1.x);
            float4 vb = fp8x4_to_f32(w1.y);
            int* a = &acc[cp ^ 1][d1][q * 8];
            atomicAdd(&a[0], (int)(va.x * SCALE2));
            atomicAdd(&a[1], (int)(va.y * SCALE2));
            atomicAdd(&a[2], (int)(va.z * SCALE2));
            atomicAdd(&a[3], (int)(va.w * SCALE2));
            atomicAdd(&a[4], (int)(vb.x * SCALE2));
            atomicAdd(&a[5], (int)(vb.y * SCALE2));
            atomicAdd(&a[6], (int)(vb.z * SCALE2));
            atomicAdd(&a[7], (int)(vb.w * SCALE2));
        }
    }
    __syncthreads();

    // merge copy 1 into copy 0
    for (int i = t; i < 256 * 33; i += 1024) ((int*)acc[0])[i] += ((int*)acc[1])[i];
    __syncthreads();

    // epilogue: 4 threads per node, 8 features each
    int n = t >> 2;
    int node = b * BSZ + n;
    if (n < BSZ && node < N_NODES) {
        float sc = (1.0f / SCALE2) / fmaxf(deg_f[node], 1.0f);
        const float* rr = r2 + (size_t)node * F_E + 8 * q;
        float e[8];
        #pragma unroll
        for (int j = 0; j < 8; ++j)
            e[j] = fmaxf((float)acc[0][n][8 * q + j] * sc + rr[j], 0.0f);
        float4* ep = (float4*)(emb + (size_t)node * F_E + 8 * q);
        ep[0] = make_float4(e[0], e[1], e[2], e[3]);
        ep[1] = make_float4(e[4], e[5], e[6], e[7]);
        float c0 = 0.f, c1 = 0.f, c2 = 0.f;
        #pragma unroll
        for (int j = 0; j < 8; ++j) {
            const float* w = Wc + (8 * q + j) * 3;
            c0 += e[j] * w[0];
            c1 += e[j] * w[1];
            c2 += e[j] * w[2];
        }
        c0 += __shfl_xor(c0, 1); c1 += __shfl_xor(c1, 1); c2 += __shfl_xor(c2, 1);
        c0 += __shfl_xor(c0, 2); c1 += __shfl_xor(c1, 2); c2 += __shfl_xor(c2, 2);
        if (q == 0) {
            logits[(size_t)node * 3 + 0] = c0 + bc[0];
            logits[(size_t)node * 3 + 1] = c1 + bc[1];
            logits[(size_t)node * 3 + 2] = c2 + bc[2];
        }
    }
}

extern "C" void kernel_launch(void* const* d_in, const int* in_sizes, int n_in,
                              void* d_out, int out_size, void* d_ws, size_t ws_size,
                              hipStream_t stream) {
    const float* x   = (const float*)d_in[0];
    const int*   ei  = (const int*)d_in[1];
    const float* W1l = (const float*)d_in[2];
    const float* W1r = (const float*)d_in[3];
    const float* b1  = (const float*)d_in[4];
    const float* W2l = (const float*)d_in[5];
    const float* W2r = (const float*)d_in[6];
    const float* b2  = (const float*)d_in[7];
    const float* Wc  = (const float*)d_in[8];
    const float* bc  = (const float*)d_in[9];

    const int* src = ei;
    const int* dst = ei + E_EDGES;

    float* out    = (float*)d_out;
    float* logits = out;
    float* emb    = out + (size_t)N_NODES * 3;

    // ws layout (4B units):
    //   deg_f (N) | cursor(512) | pairs (NB*CAP) | r2 (32N) | p8 (8N)
    //   | xh (6N: [N][12] halves)
    int* ws_i     = (int*)d_ws;
    float* deg_f  = (float*)ws_i;
    int* cursor   = ws_i + N_NODES;
    unsigned int* pairs = (unsigned int*)(cursor + 512);
    int* base2    = (int*)(pairs + (size_t)NB * CAP);
    float* r2     = (float*)base2;                                       // 32N
    unsigned char* p8 = (unsigned char*)(base2 + (size_t)32 * N_NODES);  // 8N units
    _Float16* xh  = (_Float16*)(base2 + (size_t)40 * N_NODES);           // 6N units

    hipMemsetAsync(cursor, 0, 512 * sizeof(int), stream);

    binA_kernel<<<NWG_A, 1024, 0, stream>>>(x, src, dst, cursor, pairs, xh);
    aggproj_kernel<<<NB, 1024, 0, stream>>>(
        pairs, cursor, xh, x, W1l, W1r, b1, W2l, W2r, b2, deg_f, p8, r2);
    layer2_kernel<<<NB, 1024, 0, stream>>>(
        pairs, cursor, deg_f, p8, r2, Wc, bc, emb, logits);
}